// Round 13
// baseline (506.144 us; speedup 1.0000x reference)
//
#include <hip/hip_runtime.h>
#include <hip/hip_bf16.h>
#include <math.h>

#define N_NODES 204800
#define B_GRAPHS 4096
#define DIM 128

typedef __attribute__((ext_vector_type(8))) short bf16x8;
typedef __attribute__((ext_vector_type(4))) float f32x4;

__device__ __forceinline__ float sigf(float x) {
    return 1.0f / (1.0f + __expf(-x));
}

__device__ __forceinline__ unsigned short bfrne(float x) {
    unsigned u = __float_as_uint(x);
    unsigned r = u + 0x7FFFu + ((u >> 16) & 1u);
    return (unsigned short)(r >> 16);
}

// ---------------------------------------------------------------------------
// Kernel 1: q-projection | Wt (row-major) + Wf (fragment-ordered) | bounds
// ---------------------------------------------------------------------------
__global__ __launch_bounds__(128) void qkernel(
    const float* __restrict__ feat, const float* __restrict__ U_feat,
    const float* __restrict__ W_user, const float* __restrict__ b_user,
    const float* __restrict__ W_last, const int* __restrict__ last_nodes,
    const float* __restrict__ W_key, unsigned short* __restrict__ Wt,
    unsigned short* __restrict__ Wf, const int* __restrict__ seg,
    int* __restrict__ bounds, float* __restrict__ q) {
  if (blockIdx.x >= 576) {
    int n = (blockIdx.x - 576) * 128 + threadIdx.x;
    int sc = seg[n];
    int sp = (n == 0) ? -1 : seg[n - 1];
    for (int b = sp + 1; b <= sc; ++b) bounds[b] = (b == 0) ? 0 : n;
    if (n == N_NODES - 1)
      for (int b = sc + 1; b <= B_GRAPHS; ++b) bounds[b] = N_NODES;
    return;
  }
  if (blockIdx.x >= 512) {
    int b = blockIdx.x - 512;  // 0..63
    // Wt: row-major transposed [col][k]
#pragma unroll
    for (int jj = 0; jj < 2; ++jj) {
      int o = b * 256 + jj * 128 + threadIdx.x;
      int c = o >> 7, k = o & 127;
      Wt[o] = bfrne(W_key[k * DIM + c]);
    }
    // Wf: fragment table Wf[((c*4+ks)*64+l)*8+j]
#pragma unroll
    for (int jj = 0; jj < 2; ++jj) {
      int o = b * 256 + jj * 128 + threadIdx.x;
      int j = o & 7;
      int l = (o >> 3) & 63;
      int ks = (o >> 9) & 3;
      int c = o >> 11;
      int k = ks * 32 + (l >> 4) * 8 + j;
      int row = c * 16 + (l & 15);
      Wf[o] = bfrne(W_key[k * DIM + row]);
    }
    return;
  }
  __shared__ float sU[8][DIM];
  __shared__ float sL[8][DIM];
  const int d = threadIdx.x;
  const int g0 = blockIdx.x * 8;
  for (int g = 0; g < 8; ++g) {
    sU[g][d] = U_feat[(g0 + g) * DIM + d];
    int ln = last_nodes[g0 + g];
    sL[g][d] = feat[ln * DIM + d];
  }
  __syncthreads();
  float acc[8];
#pragma unroll
  for (int g = 0; g < 8; ++g) acc[g] = 0.0f;
  for (int kk = 0; kk < 32; ++kk) {
    float wu[4], wl[4];
#pragma unroll
    for (int j = 0; j < 4; ++j) {
      wu[j] = W_user[(kk * 4 + j) * DIM + d];
      wl[j] = W_last[(kk * 4 + j) * DIM + d];
    }
#pragma unroll
    for (int g = 0; g < 8; ++g) {
      float4 u4 = reinterpret_cast<const float4*>(sU[g])[kk];
      float4 l4 = reinterpret_cast<const float4*>(sL[g])[kk];
      acc[g] += u4.x * wu[0] + u4.y * wu[1] + u4.z * wu[2] + u4.w * wu[3];
      acc[g] += l4.x * wl[0] + l4.y * wl[1] + l4.z * wl[2] + l4.w * wl[3];
    }
  }
  float bu = b_user[d];
  for (int g = 0; g < 8; ++g) q[(g0 + g) * DIM + d] = acc[g] + bu;
}

// ---------------------------------------------------------------------------
// Kernel 2 (REAL, R9 verbatim): e[n] = sigmoid(q+fk).w_e + log(cnt)
// ---------------------------------------------------------------------------
__global__ __launch_bounds__(512, 4) void ekernel(
    const float* __restrict__ feat, const unsigned short* __restrict__ Wt,
    const float* __restrict__ w_e, const float* __restrict__ cnt,
    const int* __restrict__ seg, const float* __restrict__ q,
    float* __restrict__ e) {
  __shared__ unsigned short sW[128 * DIM];
  __shared__ float sWe[DIM];
  const int tid = threadIdx.x;
  const int base = blockIdx.x * 128;
  const int l = tid & 63, w = tid >> 6;
  const int lr = l & 15, lh = l >> 4;
  const int node = base + w * 16 + lr;

  const int sg = seg[node];
  const float lc = cnt[node];

  const float* rp = feat + (size_t)node * DIM + lh * 8;
  float4 fv[4][2];
#pragma unroll
  for (int ks = 0; ks < 4; ++ks) {
    fv[ks][0] = *reinterpret_cast<const float4*>(rp + ks * 32);
    fv[ks][1] = *reinterpret_cast<const float4*>(rp + ks * 32 + 4);
  }

  const uint4* Wt4 = reinterpret_cast<const uint4*>(Wt);
#pragma unroll
  for (int i = 0; i < 4; ++i) {
    int hw = i * 4096 + tid * 8;
    int row = hw >> 7, k0 = hw & 127;
    uint4 wv = Wt4[i * 512 + tid];
    *reinterpret_cast<uint4*>(&sW[row * DIM + (k0 ^ ((row & 7) << 3))]) = wv;
  }
  if (tid < 32)
    reinterpret_cast<float4*>(sWe)[tid] =
        reinterpret_cast<const float4*>(w_e)[tid];

  const float4* q4p = reinterpret_cast<const float4*>(q);
  float4 qv[4];
#pragma unroll
  for (int c = 0; c < 4; ++c) qv[c] = q4p[(size_t)sg * 32 + c * 4 + lh];

  bf16x8 af[4];
#pragma unroll
  for (int ks = 0; ks < 4; ++ks) {
    union { bf16x8 v; unsigned short u[8]; } a;
    a.u[0] = bfrne(fv[ks][0].x); a.u[1] = bfrne(fv[ks][0].y);
    a.u[2] = bfrne(fv[ks][0].z); a.u[3] = bfrne(fv[ks][0].w);
    a.u[4] = bfrne(fv[ks][1].x); a.u[5] = bfrne(fv[ks][1].y);
    a.u[6] = bfrne(fv[ks][1].z); a.u[7] = bfrne(fv[ks][1].w);
    af[ks] = a.v;
  }

  __syncthreads();

  float4 qv2[4];
#pragma unroll
  for (int c = 0; c < 4; ++c) qv2[c] = q4p[(size_t)sg * 32 + 16 + c * 4 + lh];

  float p = 0.0f;
#pragma unroll
  for (int c = 0; c < 8; ++c) {
    const int row = c * 16 + lr;
    bf16x8 wf[4];
#pragma unroll
    for (int ks = 0; ks < 4; ++ks)
      wf[ks] = *reinterpret_cast<const bf16x8*>(
          &sW[row * DIM + ((ks * 32 + lh * 8) ^ ((row & 7) << 3))]);
    float4 we = *reinterpret_cast<const float4*>(&sWe[c * 16 + lh * 4]);

    f32x4 a0 = f32x4{0.f, 0.f, 0.f, 0.f};
#pragma unroll
    for (int ks = 0; ks < 4; ++ks)
      a0 = __builtin_amdgcn_mfma_f32_16x16x32_bf16(wf[ks], af[ks], a0, 0, 0, 0);

    float4 qc = (c < 4) ? qv[c & 3] : qv2[c & 3];
    p += we.x * sigf(a0[0] + qc.x) + we.y * sigf(a0[1] + qc.y) +
         we.z * sigf(a0[2] + qc.z) + we.w * sigf(a0[3] + qc.w);
  }

  p += __shfl_xor(p, 16, 64);
  p += __shfl_xor(p, 32, 64);
  if (lh == 0) e[node] = p + __logf(lc);
}

// ---------------------------------------------------------------------------
// Kernel 3 (REAL, R11): wave-per-graph softmax + weighted sum, no max pass.
// ---------------------------------------------------------------------------
__global__ __launch_bounds__(256) void skernel(
    const float* __restrict__ feat, const int* __restrict__ bounds,
    const float* __restrict__ e, float* __restrict__ rst) {
  const int wave = threadIdx.x >> 6;
  const int lane = threadIdx.x & 63;
  const int g = blockIdx.x * 4 + wave;
  const int s0 = bounds[g], s1 = bounds[g + 1];
  if (s1 <= s0) {
    if (lane < 32)
      reinterpret_cast<float4*>(rst)[(size_t)g * 32 + lane] =
          float4{0.f, 0.f, 0.f, 0.f};
    return;
  }
  float ls = 0.0f;
  for (int i = s0 + lane; i < s1; i += 64) ls += __expf(e[i]);
#pragma unroll
  for (int off = 32; off >= 1; off >>= 1) ls += __shfl_xor(ls, off, 64);
  const float inv = 1.0f / ls;
  const int c = lane & 31;
  const int h = lane >> 5;
  float4 acc = float4{0.f, 0.f, 0.f, 0.f};
  const float4* feat4 = reinterpret_cast<const float4*>(feat);
  for (int n = s0 + h; n < s1; n += 2) {
    float pp = __expf(e[n]);
    float4 f = feat4[(size_t)n * 32 + c];
    acc.x += pp * f.x; acc.y += pp * f.y;
    acc.z += pp * f.z; acc.w += pp * f.w;
  }
  acc.x += __shfl_xor(acc.x, 32, 64);
  acc.y += __shfl_xor(acc.y, 32, 64);
  acc.z += __shfl_xor(acc.z, 32, 64);
  acc.w += __shfl_xor(acc.w, 32, 64);
  if (h == 0) {
    float4 r;
    r.x = acc.x * inv; r.y = acc.y * inv; r.z = acc.z * inv; r.w = acc.w * inv;
    reinterpret_cast<float4*>(rst)[(size_t)g * 32 + c] = r;
  }
}

// ===========================================================================
// ABLATION kernels (diagnostic; write to scratch only). Each repeats `reps`
// times with a repeat-dependent node offset to defeat hoisting/CSE.
// ===========================================================================

// A_full: R9 ekernel body, scratch output.
__global__ __launch_bounds__(512, 4) void abl_full(
    const float* __restrict__ feat, const unsigned short* __restrict__ Wt,
    const float* __restrict__ w_e, const float* __restrict__ cnt,
    const int* __restrict__ seg, const float* __restrict__ q,
    float* __restrict__ abl, int reps) {
  __shared__ unsigned short sW[128 * DIM];
  __shared__ float sWe[DIM];
  const int tid = threadIdx.x;
  const int base = blockIdx.x * 128;
  const int l = tid & 63, w = tid >> 6;
  const int lr = l & 15, lh = l >> 4;
  const uint4* Wt4 = reinterpret_cast<const uint4*>(Wt);
  const float4* q4p = reinterpret_cast<const float4*>(q);

  for (int r = 0; r < reps; ++r) {
    int node = base + w * 16 + lr + r * 4096;
    if (node >= N_NODES) node -= N_NODES;

    const int sg = seg[node];
    const float lc = cnt[node];

    const float* rp = feat + (size_t)node * DIM + lh * 8;
    float4 fv[4][2];
#pragma unroll
    for (int ks = 0; ks < 4; ++ks) {
      fv[ks][0] = *reinterpret_cast<const float4*>(rp + ks * 32);
      fv[ks][1] = *reinterpret_cast<const float4*>(rp + ks * 32 + 4);
    }
#pragma unroll
    for (int i = 0; i < 4; ++i) {
      int hw = i * 4096 + tid * 8;
      int row = hw >> 7, k0 = hw & 127;
      uint4 wv = Wt4[i * 512 + tid];
      *reinterpret_cast<uint4*>(&sW[row * DIM + (k0 ^ ((row & 7) << 3))]) = wv;
    }
    if (tid < 32)
      reinterpret_cast<float4*>(sWe)[tid] =
          reinterpret_cast<const float4*>(w_e)[tid];

    float4 qv[4];
#pragma unroll
    for (int c = 0; c < 4; ++c) qv[c] = q4p[(size_t)sg * 32 + c * 4 + lh];

    bf16x8 af[4];
#pragma unroll
    for (int ks = 0; ks < 4; ++ks) {
      union { bf16x8 v; unsigned short u[8]; } a;
      a.u[0] = bfrne(fv[ks][0].x); a.u[1] = bfrne(fv[ks][0].y);
      a.u[2] = bfrne(fv[ks][0].z); a.u[3] = bfrne(fv[ks][0].w);
      a.u[4] = bfrne(fv[ks][1].x); a.u[5] = bfrne(fv[ks][1].y);
      a.u[6] = bfrne(fv[ks][1].z); a.u[7] = bfrne(fv[ks][1].w);
      af[ks] = a.v;
    }
    __syncthreads();

    float4 qv2[4];
#pragma unroll
    for (int c = 0; c < 4; ++c)
      qv2[c] = q4p[(size_t)sg * 32 + 16 + c * 4 + lh];

    float p = 0.0f;
#pragma unroll
    for (int c = 0; c < 8; ++c) {
      const int row = c * 16 + lr;
      bf16x8 wf[4];
#pragma unroll
      for (int ks = 0; ks < 4; ++ks)
        wf[ks] = *reinterpret_cast<const bf16x8*>(
            &sW[row * DIM + ((ks * 32 + lh * 8) ^ ((row & 7) << 3))]);
      float4 we = *reinterpret_cast<const float4*>(&sWe[c * 16 + lh * 4]);
      f32x4 a0 = f32x4{0.f, 0.f, 0.f, 0.f};
#pragma unroll
      for (int ks = 0; ks < 4; ++ks)
        a0 = __builtin_amdgcn_mfma_f32_16x16x32_bf16(wf[ks], af[ks], a0, 0, 0, 0);
      float4 qc = (c < 4) ? qv[c & 3] : qv2[c & 3];
      p += we.x * sigf(a0[0] + qc.x) + we.y * sigf(a0[1] + qc.y) +
           we.z * sigf(a0[2] + qc.z) + we.w * sigf(a0[3] + qc.w);
    }
    p += __shfl_xor(p, 16, 64);
    p += __shfl_xor(p, 32, 64);
    if (lh == 0) abl[node] = p + __logf(lc);
    __syncthreads();
  }
}

// A_noq: seg->q dependent chain removed (qc constant).
__global__ __launch_bounds__(512, 4) void abl_noq(
    const float* __restrict__ feat, const unsigned short* __restrict__ Wt,
    const float* __restrict__ w_e, const float* __restrict__ cnt,
    float* __restrict__ abl, int reps) {
  __shared__ unsigned short sW[128 * DIM];
  __shared__ float sWe[DIM];
  const int tid = threadIdx.x;
  const int base = blockIdx.x * 128;
  const int l = tid & 63, w = tid >> 6;
  const int lr = l & 15, lh = l >> 4;
  const uint4* Wt4 = reinterpret_cast<const uint4*>(Wt);

  for (int r = 0; r < reps; ++r) {
    int node = base + w * 16 + lr + r * 4096;
    if (node >= N_NODES) node -= N_NODES;
    const float lc = cnt[node];

    const float* rp = feat + (size_t)node * DIM + lh * 8;
    float4 fv[4][2];
#pragma unroll
    for (int ks = 0; ks < 4; ++ks) {
      fv[ks][0] = *reinterpret_cast<const float4*>(rp + ks * 32);
      fv[ks][1] = *reinterpret_cast<const float4*>(rp + ks * 32 + 4);
    }
#pragma unroll
    for (int i = 0; i < 4; ++i) {
      int hw = i * 4096 + tid * 8;
      int row = hw >> 7, k0 = hw & 127;
      uint4 wv = Wt4[i * 512 + tid];
      *reinterpret_cast<uint4*>(&sW[row * DIM + (k0 ^ ((row & 7) << 3))]) = wv;
    }
    if (tid < 32)
      reinterpret_cast<float4*>(sWe)[tid] =
          reinterpret_cast<const float4*>(w_e)[tid];

    bf16x8 af[4];
#pragma unroll
    for (int ks = 0; ks < 4; ++ks) {
      union { bf16x8 v; unsigned short u[8]; } a;
      a.u[0] = bfrne(fv[ks][0].x); a.u[1] = bfrne(fv[ks][0].y);
      a.u[2] = bfrne(fv[ks][0].z); a.u[3] = bfrne(fv[ks][0].w);
      a.u[4] = bfrne(fv[ks][1].x); a.u[5] = bfrne(fv[ks][1].y);
      a.u[6] = bfrne(fv[ks][1].z); a.u[7] = bfrne(fv[ks][1].w);
      af[ks] = a.v;
    }
    __syncthreads();

    const float4 qc = float4{0.1f, 0.2f, 0.1f, 0.2f};
    float p = 0.0f;
#pragma unroll
    for (int c = 0; c < 8; ++c) {
      const int row = c * 16 + lr;
      bf16x8 wf[4];
#pragma unroll
      for (int ks = 0; ks < 4; ++ks)
        wf[ks] = *reinterpret_cast<const bf16x8*>(
            &sW[row * DIM + ((ks * 32 + lh * 8) ^ ((row & 7) << 3))]);
      float4 we = *reinterpret_cast<const float4*>(&sWe[c * 16 + lh * 4]);
      f32x4 a0 = f32x4{0.f, 0.f, 0.f, 0.f};
#pragma unroll
      for (int ks = 0; ks < 4; ++ks)
        a0 = __builtin_amdgcn_mfma_f32_16x16x32_bf16(wf[ks], af[ks], a0, 0, 0, 0);
      p += we.x * sigf(a0[0] + qc.x) + we.y * sigf(a0[1] + qc.y) +
           we.z * sigf(a0[2] + qc.z) + we.w * sigf(a0[3] + qc.w);
    }
    p += __shfl_xor(p, 16, 64);
    p += __shfl_xor(p, 32, 64);
    if (lh == 0) abl[node] = p + __logf(lc);
    __syncthreads();
  }
}

// A_nofeat: feat loads removed (af synthesized per-lane, r-dependent).
__global__ __launch_bounds__(512, 4) void abl_nofeat(
    const unsigned short* __restrict__ Wt, const float* __restrict__ w_e,
    const float* __restrict__ cnt, const int* __restrict__ seg,
    const float* __restrict__ q, float* __restrict__ abl, int reps) {
  __shared__ unsigned short sW[128 * DIM];
  __shared__ float sWe[DIM];
  const int tid = threadIdx.x;
  const int base = blockIdx.x * 128;
  const int l = tid & 63, w = tid >> 6;
  const int lr = l & 15, lh = l >> 4;
  const uint4* Wt4 = reinterpret_cast<const uint4*>(Wt);
  const float4* q4p = reinterpret_cast<const float4*>(q);

  for (int r = 0; r < reps; ++r) {
    int node = base + w * 16 + lr + r * 4096;
    if (node >= N_NODES) node -= N_NODES;
    const int sg = seg[node];
    const float lc = cnt[node];

#pragma unroll
    for (int i = 0; i < 4; ++i) {
      int hw = i * 4096 + tid * 8;
      int row = hw >> 7, k0 = hw & 127;
      uint4 wv = Wt4[i * 512 + tid];
      *reinterpret_cast<uint4*>(&sW[row * DIM + (k0 ^ ((row & 7) << 3))]) = wv;
    }
    if (tid < 32)
      reinterpret_cast<float4*>(sWe)[tid] =
          reinterpret_cast<const float4*>(w_e)[tid];

    float4 qv[4];
#pragma unroll
    for (int c = 0; c < 4; ++c) qv[c] = q4p[(size_t)sg * 32 + c * 4 + lh];

    bf16x8 af[4];
#pragma unroll
    for (int ks = 0; ks < 4; ++ks) {
      union { bf16x8 v; unsigned short u[8]; } a;
#pragma unroll
      for (int j = 0; j < 8; ++j)
        a.u[j] = (unsigned short)(0x3E00 + ((l * 8 + j + r + ks) & 63));
      af[ks] = a.v;
    }
    __syncthreads();

    float4 qv2[4];
#pragma unroll
    for (int c = 0; c < 4; ++c)
      qv2[c] = q4p[(size_t)sg * 32 + 16 + c * 4 + lh];

    float p = 0.0f;
#pragma unroll
    for (int c = 0; c < 8; ++c) {
      const int row = c * 16 + lr;
      bf16x8 wf[4];
#pragma unroll
      for (int ks = 0; ks < 4; ++ks)
        wf[ks] = *reinterpret_cast<const bf16x8*>(
            &sW[row * DIM + ((ks * 32 + lh * 8) ^ ((row & 7) << 3))]);
      float4 we = *reinterpret_cast<const float4*>(&sWe[c * 16 + lh * 4]);
      f32x4 a0 = f32x4{0.f, 0.f, 0.f, 0.f};
#pragma unroll
      for (int ks = 0; ks < 4; ++ks)
        a0 = __builtin_amdgcn_mfma_f32_16x16x32_bf16(wf[ks], af[ks], a0, 0, 0, 0);
      float4 qc = (c < 4) ? qv[c & 3] : qv2[c & 3];
      p += we.x * sigf(a0[0] + qc.x) + we.y * sigf(a0[1] + qc.y) +
           we.z * sigf(a0[2] + qc.z) + we.w * sigf(a0[3] + qc.w);
    }
    p += __shfl_xor(p, 16, 64);
    p += __shfl_xor(p, 32, 64);
    if (lh == 0) abl[node] = p + __logf(lc);
    __syncthreads();
  }
}

// A_nostage: no LDS at all; W fragments direct from global Wf (L1-hot).
__global__ __launch_bounds__(512, 4) void abl_nostage(
    const float* __restrict__ feat, const unsigned short* __restrict__ Wf,
    const float* __restrict__ w_e, const float* __restrict__ cnt,
    const int* __restrict__ seg, const float* __restrict__ q,
    float* __restrict__ abl, int reps) {
  const int tid = threadIdx.x;
  const int base = blockIdx.x * 128;
  const int l = tid & 63, w = tid >> 6;
  const int lr = l & 15, lh = l >> 4;
  const float4* q4p = reinterpret_cast<const float4*>(q);
  const bf16x8* Wfb = reinterpret_cast<const bf16x8*>(Wf);

  for (int r = 0; r < reps; ++r) {
    int node = base + w * 16 + lr + r * 4096;
    if (node >= N_NODES) node -= N_NODES;
    const int sg = seg[node];
    const float lc = cnt[node];

    const float* rp = feat + (size_t)node * DIM + lh * 8;
    float4 fv[4][2];
#pragma unroll
    for (int ks = 0; ks < 4; ++ks) {
      fv[ks][0] = *reinterpret_cast<const float4*>(rp + ks * 32);
      fv[ks][1] = *reinterpret_cast<const float4*>(rp + ks * 32 + 4);
    }

    float4 qv[4];
#pragma unroll
    for (int c = 0; c < 4; ++c) qv[c] = q4p[(size_t)sg * 32 + c * 4 + lh];

    bf16x8 af[4];
#pragma unroll
    for (int ks = 0; ks < 4; ++ks) {
      union { bf16x8 v; unsigned short u[8]; } a;
      a.u[0] = bfrne(fv[ks][0].x); a.u[1] = bfrne(fv[ks][0].y);
      a.u[2] = bfrne(fv[ks][0].z); a.u[3] = bfrne(fv[ks][0].w);
      a.u[4] = bfrne(fv[ks][1].x); a.u[5] = bfrne(fv[ks][1].y);
      a.u[6] = bfrne(fv[ks][1].z); a.u[7] = bfrne(fv[ks][1].w);
      af[ks] = a.v;
    }

    float4 qv2[4];
#pragma unroll
    for (int c = 0; c < 4; ++c)
      qv2[c] = q4p[(size_t)sg * 32 + 16 + c * 4 + lh];

    float p = 0.0f;
#pragma unroll
    for (int c = 0; c < 8; ++c) {
      bf16x8 wf[4];
#pragma unroll
      for (int ks = 0; ks < 4; ++ks) wf[ks] = Wfb[(c * 4 + ks) * 64 + l];
      float4 we = *reinterpret_cast<const float4*>(&w_e[c * 16 + lh * 4]);
      f32x4 a0 = f32x4{0.f, 0.f, 0.f, 0.f};
#pragma unroll
      for (int ks = 0; ks < 4; ++ks)
        a0 = __builtin_amdgcn_mfma_f32_16x16x32_bf16(wf[ks], af[ks], a0, 0, 0, 0);
      float4 qc = (c < 4) ? qv[c & 3] : qv2[c & 3];
      p += we.x * sigf(a0[0] + qc.x) + we.y * sigf(a0[1] + qc.y) +
           we.z * sigf(a0[2] + qc.z) + we.w * sigf(a0[3] + qc.w);
    }
    p += __shfl_xor(p, 16, 64);
    p += __shfl_xor(p, 32, 64);
    if (lh == 0) abl[node] = p + __logf(lc);
  }
}

// ---------------------------------------------------------------------------
extern "C" void kernel_launch(void* const* d_in, const int* in_sizes, int n_in,
                              void* d_out, int out_size, void* d_ws,
                              size_t ws_size, hipStream_t stream) {
  const float* feat = (const float*)d_in[0];
  const float* U_feat = (const float*)d_in[1];
  const float* cnt = (const float*)d_in[2];
  const float* W_key = (const float*)d_in[3];
  const float* W_user = (const float*)d_in[4];
  const float* b_user = (const float*)d_in[5];
  const float* W_last = (const float*)d_in[6];
  const float* w_e = (const float*)d_in[7];
  const int* last_nodes = (const int*)d_in[8];
  const int* seg = (const int*)d_in[9];
  float* out = (float*)d_out;

  float* q = (float*)d_ws;                       // 4096*128 f32 (2 MB)
  float* e = q + B_GRAPHS * DIM;                 // 204800 f32
  unsigned short* Wt = (unsigned short*)(e + N_NODES);   // 32 KB
  unsigned short* Wf = Wt + DIM * DIM;           // 32 KB
  int* bounds = (int*)(Wf + DIM * DIM);          // 4097 ints
  float* abl = (float*)((char*)d_ws + (64u << 20));  // scratch @ +64 MB

  // real pipeline (correct output)
  qkernel<<<512 + 64 + N_NODES / 128, 128, 0, stream>>>(
      feat, U_feat, W_user, b_user, W_last, last_nodes, W_key, Wt, Wf, seg,
      bounds, q);
  ekernel<<<N_NODES / 128, 512, 0, stream>>>(feat, Wt, w_e, cnt, seg, q, e);
  skernel<<<B_GRAPHS / 4, 256, 0, stream>>>(feat, bounds, e, out);

  // ablation dispatches (scratch only)
  abl_full<<<N_NODES / 128, 512, 0, stream>>>(feat, Wt, w_e, cnt, seg, q,
                                              abl, 2);
  abl_noq<<<N_NODES / 128, 512, 0, stream>>>(feat, Wt, w_e, cnt,
                                             abl + N_NODES, 4);
  abl_nofeat<<<N_NODES / 128, 512, 0, stream>>>(Wt, w_e, cnt, seg, q,
                                                abl + 2 * N_NODES, 4);
  abl_nostage<<<N_NODES / 128, 512, 0, stream>>>(feat, Wf, w_e, cnt, seg, q,
                                                 abl + 3 * N_NODES, 2);
}

// Round 14
// 75.418 us; speedup vs baseline: 6.7112x; 6.7112x over previous
//
#include <hip/hip_runtime.h>
#include <hip/hip_bf16.h>
#include <math.h>

#define N_NODES 204800
#define B_GRAPHS 4096
#define DIM 128

typedef __attribute__((ext_vector_type(8))) short bf16x8;
typedef __attribute__((ext_vector_type(4))) float f32x4;

__device__ __forceinline__ float sigf(float x) {
    return 1.0f / (1.0f + __expf(-x));
}

__device__ __forceinline__ unsigned short bfrne(float x) {
    unsigned u = __float_as_uint(x);
    unsigned r = u + 0x7FFFu + ((u >> 16) & 1u);
    return (unsigned short)(r >> 16);
}

// ---------------------------------------------------------------------------
// Kernel 1, three jobs by blockIdx.x:
//   [0..512):    q[b] = U_feat[b]@W_user + b_user + feat[last[b]]@W_last
//   [512..576):  Wt_bf16[c][k] = bf16(W_key[k][c])
//   [576..2176): bounds scatter (segments sorted & contiguous)
// ---------------------------------------------------------------------------
__global__ __launch_bounds__(128) void qkernel(
    const float* __restrict__ feat, const float* __restrict__ U_feat,
    const float* __restrict__ W_user, const float* __restrict__ b_user,
    const float* __restrict__ W_last, const int* __restrict__ last_nodes,
    const float* __restrict__ W_key, unsigned short* __restrict__ Wt,
    const int* __restrict__ seg, int* __restrict__ bounds,
    float* __restrict__ q) {
  if (blockIdx.x >= 576) {
    int n = (blockIdx.x - 576) * 128 + threadIdx.x;
    int sc = seg[n];
    int sp = (n == 0) ? -1 : seg[n - 1];
    for (int b = sp + 1; b <= sc; ++b) bounds[b] = (b == 0) ? 0 : n;
    if (n == N_NODES - 1)
      for (int b = sc + 1; b <= B_GRAPHS; ++b) bounds[b] = N_NODES;
    return;
  }
  if (blockIdx.x >= 512) {
    int b = blockIdx.x - 512;  // 0..63
#pragma unroll
    for (int j = 0; j < 2; ++j) {
      int o = b * 256 + j * 128 + threadIdx.x;
      int c = o >> 7, k = o & 127;
      Wt[o] = bfrne(W_key[k * DIM + c]);
    }
    return;
  }
  __shared__ float sU[8][DIM];
  __shared__ float sL[8][DIM];
  const int d = threadIdx.x;
  const int g0 = blockIdx.x * 8;
  for (int g = 0; g < 8; ++g) {
    sU[g][d] = U_feat[(g0 + g) * DIM + d];
    int ln = last_nodes[g0 + g];
    sL[g][d] = feat[ln * DIM + d];
  }
  __syncthreads();
  float acc[8];
#pragma unroll
  for (int g = 0; g < 8; ++g) acc[g] = 0.0f;
  for (int kk = 0; kk < 32; ++kk) {
    float wu[4], wl[4];
#pragma unroll
    for (int j = 0; j < 4; ++j) {
      wu[j] = W_user[(kk * 4 + j) * DIM + d];
      wl[j] = W_last[(kk * 4 + j) * DIM + d];
    }
#pragma unroll
    for (int g = 0; g < 8; ++g) {
      float4 u4 = reinterpret_cast<const float4*>(sU[g])[kk];
      float4 l4 = reinterpret_cast<const float4*>(sL[g])[kk];
      acc[g] += u4.x * wu[0] + u4.y * wu[1] + u4.z * wu[2] + u4.w * wu[3];
      acc[g] += l4.x * wl[0] + l4.y * wl[1] + l4.z * wl[2] + l4.w * wl[3];
    }
  }
  float bu = b_user[d];
  for (int g = 0; g < 8; ++g) q[(g0 + g) * DIM + d] = acc[g] + bu;
}

// ---------------------------------------------------------------------------
// Kernel 2 (fully fused, wave-per-graph): for wave's graph g, per 16-node
// tile: e = sigmoid(q[g] + feat@W_key).w_e (swapped-operand MFMA, verified);
// xor-reduce leaves e on ALL lanes; w = cnt*exp(e_pre) (log/exp cancel, no
// max pass — bounded, R11-verified); accumulate s += w, acc += w*fv while
// fv is still in registers => softmax + weighted sum fused, feat read ONCE,
// no seg loads (graph id known), q row loaded at t=0 under W staging.
// Grid: 1024 blocks x 256 thr (4 waves = 4 graphs per block).
// ---------------------------------------------------------------------------
__global__ __launch_bounds__(256) void gkernel(
    const float* __restrict__ feat, const unsigned short* __restrict__ Wt,
    const float* __restrict__ w_e, const float* __restrict__ cnt,
    const int* __restrict__ bounds, const float* __restrict__ q,
    float* __restrict__ rst) {
  __shared__ unsigned short sW[128 * DIM];
  __shared__ float sWe[DIM];
  const int tid = threadIdx.x;
  const int l = tid & 63, w = tid >> 6;
  const int lr = l & 15, lh = l >> 4;
  const int g = blockIdx.x * 4 + w;

  // ---- per-wave scalars + q row (independent loads, issue immediately)
  const int s0 = bounds[g], s1 = bounds[g + 1];
  const float4* q4p = reinterpret_cast<const float4*>(q);
  float4 qv[8];
#pragma unroll
  for (int c = 0; c < 8; ++c) qv[c] = q4p[(size_t)g * 32 + c * 4 + lh];

  // ---- stage Wt (XOR-swizzled, R9-proven) + w_e
  const uint4* Wt4 = reinterpret_cast<const uint4*>(Wt);
#pragma unroll
  for (int i = 0; i < 8; ++i) {
    int hw = i * 2048 + tid * 8;
    int row = hw >> 7, k0 = hw & 127;
    uint4 wv = Wt4[i * 256 + tid];
    *reinterpret_cast<uint4*>(&sW[row * DIM + (k0 ^ ((row & 7) << 3))]) = wv;
  }
  if (tid < 32)
    reinterpret_cast<float4*>(sWe)[tid] =
        reinterpret_cast<const float4*>(w_e)[tid];

  __syncthreads();  // only barrier

  if (s1 <= s0) {  // empty graph -> zero row
    if (l < 32)
      reinterpret_cast<float4*>(rst)[(size_t)g * 32 + l] =
          float4{0.f, 0.f, 0.f, 0.f};
    return;
  }

  float4 acc[4][2];
#pragma unroll
  for (int ks = 0; ks < 4; ++ks) {
    acc[ks][0] = float4{0.f, 0.f, 0.f, 0.f};
    acc[ks][1] = float4{0.f, 0.f, 0.f, 0.f};
  }
  float s = 0.0f;

  const int ntiles = (s1 - s0 + 15) >> 4;
  for (int t = 0; t < ntiles; ++t) {
    const int node = s0 + t * 16 + lr;
    const bool valid = node < s1;
    const int nc = valid ? node : (s1 - 1);

    // ---- feat tile (8 float4 burst, contiguous 8KB per tile)
    const float* rp = feat + (size_t)nc * DIM + lh * 8;
    float4 fv[4][2];
#pragma unroll
    for (int ks = 0; ks < 4; ++ks) {
      fv[ks][0] = *reinterpret_cast<const float4*>(rp + ks * 32);
      fv[ks][1] = *reinterpret_cast<const float4*>(rp + ks * 32 + 4);
    }
    const float lc = cnt[nc];

    bf16x8 af[4];
#pragma unroll
    for (int ks = 0; ks < 4; ++ks) {
      union { bf16x8 v; unsigned short u[8]; } a;
      a.u[0] = bfrne(fv[ks][0].x); a.u[1] = bfrne(fv[ks][0].y);
      a.u[2] = bfrne(fv[ks][0].z); a.u[3] = bfrne(fv[ks][0].w);
      a.u[4] = bfrne(fv[ks][1].x); a.u[5] = bfrne(fv[ks][1].y);
      a.u[6] = bfrne(fv[ks][1].z); a.u[7] = bfrne(fv[ks][1].w);
      af[ks] = a.v;
    }

    // ---- e partial: D[keycol = c*16 + 4*lh + r][node = lr]
    float p = 0.0f;
#pragma unroll
    for (int c = 0; c < 8; ++c) {
      const int row = c * 16 + lr;
      bf16x8 wf[4];
#pragma unroll
      for (int ks = 0; ks < 4; ++ks)
        wf[ks] = *reinterpret_cast<const bf16x8*>(
            &sW[row * DIM + ((ks * 32 + lh * 8) ^ ((row & 7) << 3))]);
      float4 we = *reinterpret_cast<const float4*>(&sWe[c * 16 + lh * 4]);

      f32x4 a0 = f32x4{0.f, 0.f, 0.f, 0.f};
#pragma unroll
      for (int ks = 0; ks < 4; ++ks)
        a0 = __builtin_amdgcn_mfma_f32_16x16x32_bf16(wf[ks], af[ks], a0, 0, 0, 0);

      float4 qc = qv[c];
      p += we.x * sigf(a0[0] + qc.x) + we.y * sigf(a0[1] + qc.y) +
           we.z * sigf(a0[2] + qc.z) + we.w * sigf(a0[3] + qc.w);
    }
    // xor-reduce over lh: ALL lanes end with the full e_pre of node lr
    p += __shfl_xor(p, 16, 64);
    p += __shfl_xor(p, 32, 64);

    // ---- fused softmax weight + weighted feature accumulation
    const float wt = valid ? lc * __expf(p) : 0.0f;
    s += wt;
#pragma unroll
    for (int ks = 0; ks < 4; ++ks) {
      acc[ks][0].x += wt * fv[ks][0].x; acc[ks][0].y += wt * fv[ks][0].y;
      acc[ks][0].z += wt * fv[ks][0].z; acc[ks][0].w += wt * fv[ks][0].w;
      acc[ks][1].x += wt * fv[ks][1].x; acc[ks][1].y += wt * fv[ks][1].y;
      acc[ks][1].z += wt * fv[ks][1].z; acc[ks][1].w += wt * fv[ks][1].w;
    }
  }

  // ---- reduce over the 16 lr lanes (xor 1,2,4,8)
#pragma unroll
  for (int m = 1; m <= 8; m <<= 1) {
    s += __shfl_xor(s, m, 64);
#pragma unroll
    for (int ks = 0; ks < 4; ++ks)
#pragma unroll
      for (int jh = 0; jh < 2; ++jh) {
        acc[ks][jh].x += __shfl_xor(acc[ks][jh].x, m, 64);
        acc[ks][jh].y += __shfl_xor(acc[ks][jh].y, m, 64);
        acc[ks][jh].z += __shfl_xor(acc[ks][jh].z, m, 64);
        acc[ks][jh].w += __shfl_xor(acc[ks][jh].w, m, 64);
      }
  }

  const float inv = 1.0f / s;
  // lane lr in [0,8): writes float4 chunk (ks = lr>>1, jh = lr&1) of its
  // lh block: col = ks*32 + lh*8 + jh*4 -> float4 idx = ks*8 + lh*2 + jh
  if (lr < 8) {
    const int ks = lr >> 1, jh = lr & 1;
    float4 v;
    v.x = acc[ks][jh].x * inv; v.y = acc[ks][jh].y * inv;
    v.z = acc[ks][jh].z * inv; v.w = acc[ks][jh].w * inv;
    reinterpret_cast<float4*>(rst)[(size_t)g * 32 + ks * 8 + lh * 2 + jh] = v;
  }
}

// ---------------------------------------------------------------------------
extern "C" void kernel_launch(void* const* d_in, const int* in_sizes, int n_in,
                              void* d_out, int out_size, void* d_ws,
                              size_t ws_size, hipStream_t stream) {
  const float* feat = (const float*)d_in[0];
  const float* U_feat = (const float*)d_in[1];
  const float* cnt = (const float*)d_in[2];
  const float* W_key = (const float*)d_in[3];
  const float* W_user = (const float*)d_in[4];
  const float* b_user = (const float*)d_in[5];
  const float* W_last = (const float*)d_in[6];
  const float* w_e = (const float*)d_in[7];
  const int* last_nodes = (const int*)d_in[8];
  const int* seg = (const int*)d_in[9];
  float* out = (float*)d_out;

  float* q = (float*)d_ws;                              // 4096*128 f32 (2 MB)
  unsigned short* Wt = (unsigned short*)(q + B_GRAPHS * DIM);  // 32 KB
  int* bounds = (int*)(Wt + DIM * DIM);                 // 4097 ints

  qkernel<<<512 + 64 + N_NODES / 128, 128, 0, stream>>>(
      feat, U_feat, W_user, b_user, W_last, last_nodes, W_key, Wt, seg,
      bounds, q);
  gkernel<<<B_GRAPHS / 4, 256, 0, stream>>>(feat, Wt, w_e, cnt, bounds, q, out);
}